// Round 1
// baseline (959.872 us; speedup 1.0000x reference)
//
#include <hip/hip_runtime.h>

static constexpr int S  = 2048;
static constexpr int E  = 128;
static constexpr int V  = 50257;

static constexpr int MB = 128;   // block tile M
static constexpr int NB = 48;    // block tile N
static constexpr int KC = 32;    // K chunk = one MFMA K-step
static constexpr int KP = 40;    // padded LDS row stride (bf16 elems, 80 B, 16B-aligned)

typedef __attribute__((ext_vector_type(8))) short bf16x8;
typedef __attribute__((ext_vector_type(4))) float floatx4;

#define MF(a, b, c) __builtin_amdgcn_mfma_f32_16x16x32_bf16((a), (b), (c), 0, 0, 0)

// Split fp32 into bf16 hi + bf16 lo (truncation split: exact to ~2^-16 rel).
__device__ __forceinline__ void split2(float x, unsigned short& hi, unsigned short& lo) {
    unsigned xb = __float_as_uint(x);
    hi = (unsigned short)(xb >> 16);
    float hf = __uint_as_float(xb & 0xFFFF0000u);
    lo = (unsigned short)(__float_as_uint(x - hf) >> 16);
}

__global__ __launch_bounds__(256, 2)
void interference_kernel(const float* __restrict__ psi_r,
                         const float* __restrict__ psi_i,
                         const float* __restrict__ pat_r,
                         const float* __restrict__ pat_i,
                         const float* __restrict__ Wm,
                         const float* __restrict__ bias,
                         float* __restrict__ out)
{
    // sA mats: 0 Pr_hi, 1 Pr_lo, 2 Pi_hi, 3 Pi_lo   [mat][row<128][KP]
    // sB mats: 0 qr_hi, 1 qr_lo, 2 qi_hi, 3 qi_lo, 4 w_hi, 5 w_lo  [mat][row<48][KP]
    __shared__ short smem[4 * MB * KP + 6 * NB * KP];  // 64000 B
    short* sA = smem;
    short* sB = smem + 4 * MB * KP;

    const int tid  = threadIdx.x;
    const int wave = tid >> 6;
    const int lane = tid & 63;
    const int quad = lane >> 4;
    const int r16  = lane & 15;

    const int m0 = blockIdx.y * MB;
    const int v0 = blockIdx.x * NB;

    floatx4 Cr[2][3], Ci[2][3], Cl[2][3];
    #pragma unroll
    for (int mi = 0; mi < 2; mi++)
        #pragma unroll
        for (int ni = 0; ni < 3; ni++) {
            Cr[mi][ni] = floatx4{0.f, 0.f, 0.f, 0.f};
            Ci[mi][ni] = floatx4{0.f, 0.f, 0.f, 0.f};
            Cl[mi][ni] = floatx4{0.f, 0.f, 0.f, 0.f};
        }

    for (int chunk = 0; chunk < E / KC; chunk++) {
        const int kc = chunk * KC;

        // ---- stage A: psi_real / psi_imag [128 x 32] fp32 -> hi/lo bf16 in LDS
        // 2048 float4 loads total, 8 per thread
        #pragma unroll
        for (int i = 0; i < 8; i++) {
            int idx = tid + i * 256;     // 0..2047
            int src = idx >> 10;         // 0: real, 1: imag (1024 float4 per source)
            int rem = idx & 1023;
            int row = rem >> 3;
            int kq  = rem & 7;
            const float* bsrc = src ? psi_i : psi_r;
            const float4 x = *(const float4*)(bsrc + (m0 + row) * E + kc + kq * 4);
            unsigned short h0, h1, h2, h3, l0, l1, l2, l3;
            split2(x.x, h0, l0); split2(x.y, h1, l1);
            split2(x.z, h2, l2); split2(x.w, h3, l3);
            int offh = ((src * 2) * MB + row) * KP + kq * 4;
            int offl = offh + MB * KP;
            uint2 uh = make_uint2((unsigned)h0 | ((unsigned)h1 << 16),
                                  (unsigned)h2 | ((unsigned)h3 << 16));
            uint2 ul = make_uint2((unsigned)l0 | ((unsigned)l1 << 16),
                                  (unsigned)l2 | ((unsigned)l3 << 16));
            *(uint2*)(sA + offh) = uh;
            *(uint2*)(sA + offl) = ul;
        }

        // ---- stage B: patterns_real / patterns_imag / W [48 x 32] fp32 -> hi/lo bf16
        // 1152 float4 loads total
        #pragma unroll
        for (int i = 0; i < 5; i++) {
            int idx = tid + i * 256;
            if (idx < 1152) {
                int src = idx / 384;     // 0 qr, 1 qi, 2 w (384 float4 per source)
                int rem = idx - src * 384;
                int row = rem >> 3;
                int kq  = rem & 7;
                int vv  = v0 + row; if (vv > V - 1) vv = V - 1;  // clamp; store is guarded
                const float* bsrc = (src == 0) ? pat_r : ((src == 1) ? pat_i : Wm);
                const float4 x = *(const float4*)(bsrc + vv * E + kc + kq * 4);
                unsigned short h0, h1, h2, h3, l0, l1, l2, l3;
                split2(x.x, h0, l0); split2(x.y, h1, l1);
                split2(x.z, h2, l2); split2(x.w, h3, l3);
                int offh = ((src * 2) * NB + row) * KP + kq * 4;
                int offl = offh + NB * KP;
                uint2 uh = make_uint2((unsigned)h0 | ((unsigned)h1 << 16),
                                      (unsigned)h2 | ((unsigned)h3 << 16));
                uint2 ul = make_uint2((unsigned)l0 | ((unsigned)l1 << 16),
                                      (unsigned)l2 | ((unsigned)l3 << 16));
                *(uint2*)(sB + offh) = uh;
                *(uint2*)(sB + offl) = ul;
            }
        }
        __syncthreads();

        // ---- B fragments, resident for the chunk (18 ds_read_b128)
        bf16x8 fB[6][3];
        #pragma unroll
        for (int bm = 0; bm < 6; bm++)
            #pragma unroll
            for (int ni = 0; ni < 3; ni++)
                fB[bm][ni] = *(const bf16x8*)(sB + (bm * NB + ni * 16 + r16) * KP + quad * 8);

        // ---- MFMA: 15 products per (mi,ni) position
        #pragma unroll
        for (int mi = 0; mi < 2; mi++) {
            const int ab = (wave * 32 + mi * 16 + r16) * KP + quad * 8;
            bf16x8 Prh = *(const bf16x8*)(sA + ab);
            bf16x8 Prl = *(const bf16x8*)(sA + ab + MB * KP);
            bf16x8 Pih = *(const bf16x8*)(sA + ab + 2 * MB * KP);
            bf16x8 Pil = *(const bf16x8*)(sA + ab + 3 * MB * KP);
            #pragma unroll
            for (int ni = 0; ni < 3; ni++) {
                // C_r += Pr*qr + Pi*qi  (3-product split each)
                Cr[mi][ni] = MF(Prh, fB[0][ni], Cr[mi][ni]);
                Cr[mi][ni] = MF(Prh, fB[1][ni], Cr[mi][ni]);
                Cr[mi][ni] = MF(Prl, fB[0][ni], Cr[mi][ni]);
                Cr[mi][ni] = MF(Pih, fB[2][ni], Cr[mi][ni]);
                Cr[mi][ni] = MF(Pih, fB[3][ni], Cr[mi][ni]);
                Cr[mi][ni] = MF(Pil, fB[2][ni], Cr[mi][ni]);
                // C_i += Pr*qi
                Ci[mi][ni] = MF(Prh, fB[2][ni], Ci[mi][ni]);
                Ci[mi][ni] = MF(Prh, fB[3][ni], Ci[mi][ni]);
                Ci[mi][ni] = MF(Prl, fB[2][ni], Ci[mi][ni]);
                // C_lin += Pr*W
                Cl[mi][ni] = MF(Prh, fB[4][ni], Cl[mi][ni]);
                Cl[mi][ni] = MF(Prh, fB[5][ni], Cl[mi][ni]);
                Cl[mi][ni] = MF(Prl, fB[4][ni], Cl[mi][ni]);
            }
            // negate Pi fragments in-register (bf16 sign-bit flip)
            Pih = Pih ^ (short)0x8000;
            Pil = Pil ^ (short)0x8000;
            #pragma unroll
            for (int ni = 0; ni < 3; ni++) {
                // C_i += (-Pi)*qr
                Ci[mi][ni] = MF(Pih, fB[0][ni], Ci[mi][ni]);
                Ci[mi][ni] = MF(Pih, fB[1][ni], Ci[mi][ni]);
                Ci[mi][ni] = MF(Pil, fB[0][ni], Ci[mi][ni]);
            }
        }
        __syncthreads();
    }

    // ---- epilogue: out = Cr^2 + Ci^2 + Cl + b
    #pragma unroll
    for (int ni = 0; ni < 3; ni++) {
        const int col = v0 + ni * 16 + r16;
        if (col < V) {
            const float bv = bias[col];
            #pragma unroll
            for (int mi = 0; mi < 2; mi++) {
                const int rbase = m0 + wave * 32 + mi * 16 + quad * 4;
                #pragma unroll
                for (int r = 0; r < 4; r++) {
                    float cr = Cr[mi][ni][r];
                    float ci = Ci[mi][ni][r];
                    float cl = Cl[mi][ni][r];
                    out[(long)(rbase + r) * V + col] = cr * cr + ci * ci + cl + bv;
                }
            }
        }
    }
}

extern "C" void kernel_launch(void* const* d_in, const int* in_sizes, int n_in,
                              void* d_out, int out_size, void* d_ws, size_t ws_size,
                              hipStream_t stream) {
    const float* psi_r = (const float*)d_in[0];
    const float* psi_i = (const float*)d_in[1];
    const float* pat_r = (const float*)d_in[2];
    const float* pat_i = (const float*)d_in[3];
    const float* Wm    = (const float*)d_in[4];
    const float* b     = (const float*)d_in[5];
    float* out = (float*)d_out;

    dim3 grid((V + NB - 1) / NB, S / MB);   // 1048 x 16
    interference_kernel<<<grid, dim3(256), 0, stream>>>(psi_r, psi_i, pat_r, pat_i, Wm, b, out);
}